// Round 6
// baseline (274.557 us; speedup 1.0000x reference)
//
#include <hip/hip_runtime.h>
#include <math.h>

#define NXY    192
#define CELLS  (NXY*NXY)
#define NBATCH 4
#define NSTEPS 256
#define TCH    32                 // steps per chunk
#define NCHUNK (NSTEPS/TCH)       // 8
#define TPB    512                // 8 waves
#define RPL    10                 // valid rows per wave band
#define HC     4                  // in-register ghost rows per side
#define RT     (RPL + 2*HC)       // 18 register rows per lane
#define NSS    (TCH/HC)           // 8 supersteps per chunk
#define NBLKS  144                // 12 row-tiles x 3 col-tiles x 4 batches
// in-tile 128 wide x 80 tall; out-tile 64 wide x 16 tall

// workspace layout (float offsets)
#define K3_OFF (16*CELLS)
#define A1_OFF (K3_OFF + CELLS)
#define I_OFF  (A1_OFF + CELLS)

typedef float v2f __attribute__((ext_vector_type(2)));

__device__ __forceinline__ float dpp_up1(float v) {
    int r = __builtin_amdgcn_update_dpp(0, __builtin_bit_cast(int, v),
                                        0x138, 0xf, 0xf, true); // wave_shr:1
    return __builtin_bit_cast(float, r);
}
__device__ __forceinline__ float dpp_dn1(float v) {
    int r = __builtin_amdgcn_update_dpp(0, __builtin_bit_cast(int, v),
                                        0x130, 0xf, 0xf, true); // wave_shl:1
    return __builtin_bit_cast(float, r);
}

__device__ __forceinline__ float pml_prof(int i) {
    int t;
    if (i <= 20)            t = 20 - i;
    else if (i >= NXY - 21) t = i - (NXY - 21);
    else                    return 0.0f;
    float u  = (float)t * 0.05f;
    float u2 = u * u;
    return 3.0f * u2 * u2;
}

__global__ void setup_k(const float* __restrict__ rho, float* __restrict__ ws) {
    int idx    = blockIdx.x * blockDim.x + threadIdx.x;
    int stride = gridDim.x * blockDim.x;
    for (int k = idx; k < 8 * CELLS; k += stride) ws[k] = 0.0f;
    const float IH2 = (float)(1.0 / (2.01 * 2.01));
    for (int k = idx; k < CELLS; k += stride) {
        int i = k / NXY, j = k % NXY;
        float r0 = rho[k];
        float ru = (i > 0)       ? rho[k - NXY] : 0.0f;
        float rd = (i < NXY - 1) ? rho[k + NXY] : 0.0f;
        float rl = (j > 0)       ? rho[k - 1]   : 0.0f;
        float rr2 = (j < NXY - 1) ? rho[k + 1]  : 0.0f;
        float lpf = 0.5f * r0 + 0.125f * ((ru + rd) + (rl + rr2));
        float p   = 0.5f * (1.0f + tanhf(100.0f * (lpf - 0.5f)));
        float c   = 1.0f - 0.1f * p;
        float c2h = c * c * IH2;
        float bx = pml_prof(i), by = pml_prof(j);
        float bb = sqrtf(bx * bx + by * by);
        float a1 = 1.0f / (1.0f + 0.5f * bb);
        ws[K3_OFF + k] = a1 * c2h;     // K
        ws[A1_OFF + k] = a1;           // A1 (Q derived at load)
    }
    if (idx < 12) ws[I_OFF + idx] = 0.0f;
}

__global__ __launch_bounds__(TPB, 1)
void chunk_k(const float* __restrict__ x, float* __restrict__ ws, int chunk) {
    int blk = blockIdx.x;
    int b  = blk / 36;                // batch
    int rr = blk % 36;
    int bi = rr / 3, bj = rr % 3;     // 12 row-tiles x 3 col-tiles
    int I0 = 16 * bi - 32;            // in-tile row origin (80 rows)
    int J0 = 64 * bj - 32;            // in-tile col origin (128 cols)
    int t  = threadIdx.x;
    int w  = t >> 6;                  // wave 0..7, valid band rows [10w,10w+10)
    int l  = t & 63;                  // lane: local cols 2l, 2l+1
    int row0 = I0 + RPL * w - HC;     // global row of register row i=0
    int gj   = J0 + 2 * l;

    // exchange buffers: U[slot][row7][lane] (wave w writes slot w, top rows;
    // consumer w reads slot w+1; slot 8 = zeros). D: wave w writes slot w+1
    // (bottom rows); consumer w reads slot w; slot 0 = zeros.
    __shared__ v2f U[9][7][64];
    __shared__ v2f D[9][7][64];
    __shared__ float xs_l[TCH];
    for (int k = t; k < 9 * 7 * 64; k += TPB) {
        ((v2f*)U)[k] = (v2f){0.f, 0.f};
        ((v2f*)D)[k] = (v2f){0.f, 0.f};
    }
    if (t < TCH) xs_l[t] = x[b * NSTEPS + chunk * TCH + t];

    const float* kg = ws + K3_OFF;
    const float* ag = ws + A1_OFF;
    int pin = chunk & 1, pout = pin ^ 1;
    const float* curg  = ws + ((pin  * 2 + 0) * NBATCH + b) * CELLS;
    const float* prvg  = ws + ((pin  * 2 + 1) * NBATCH + b) * CELLS;
    float*       ncurg = ws + ((pout * 2 + 0) * NBATCH + b) * CELLS;
    float*       nprvg = ws + ((pout * 2 + 1) * NBATCH + b) * CELLS;

    v2f yc[RT], yp[RT], Qa[RT], Ka[RT];
    bool cok = (gj >= 0 && gj < NXY);
#pragma unroll
    for (int i = 0; i < RT; i++) {
        int gi = row0 + i;
        bool ok = cok && gi >= 0 && gi < NXY;
        v2f cv = {0.f,0.f}, pv = {0.f,0.f};
        if (ok) {
            int idx = gi * NXY + gj;
            cv = *(const v2f*)(curg + idx);
            pv = *(const v2f*)(prvg + idx);
        }
        yc[i] = cv; yp[i] = pv;
    }
#pragma unroll
    for (int i = 1; i < RT - 1; i++) {   // coefficients only on computed rows
        int gi = row0 + i;
        bool ok = cok && gi >= 0 && gi < NXY;
        v2f kv = {0.f,0.f}, av = {0.f,0.f};
        if (ok) {
            int idx = gi * NXY + gj;
            kv = *(const v2f*)(kg + idx);
            av = *(const v2f*)(ag + idx);
        }
        Ka[i] = kv;
        Qa[i] = ok ? (v2f){1.f - 2.f * av.x, 1.f - 2.f * av.y} : (v2f){0.f, 0.f};
    }

    // source (40,96)
    int sc = 96 - J0;
    bool wave_src = (sc >= 0 && sc < 128);
    int src_i = 40 - row0;            // register row of source (may be out of range)
    float srcm = (2 * l == sc) ? 1.f : 0.f;

    // probe: row 160, col 48*(bj+1); owner = valid-band wave only
    int prb_i = 160 - row0;
    bool wave_prb = (bi == 10) && (prb_i >= HC) && (prb_i < HC + RPL);
    float prbm = (2 * l == (48 * (bj + 1) - J0)) ? 1.f : 0.f;
    float pacc = 0.f;

// row update: yn = c + Q*(p-c) + K*(S-4c) — packed fp32
#define ROWC(CUR, PRV, rr_, XSV, YN) do {                                      \
    v2f cv = CUR[rr_];                                                         \
    float lf0 = dpp_up1(cv.y);                                                 \
    float rt1 = dpp_dn1(cv.x);                                                 \
    v2f h = (v2f){lf0, rt1} + __builtin_shufflevector(cv, cv, 1, 0);           \
    v2f S = (CUR[rr_ - 1] + CUR[rr_ + 1]) + h;                                 \
    YN = cv + Qa[rr_] * (PRV[rr_] - cv) + Ka[rr_] * (S - 4.0f * cv);           \
    if (wave_src && (rr_) == src_i) YN.x += srcm * (XSV);                      \
    if (wave_prb && (rr_) == prb_i) { float tq = prbm * YN.x; pacc += tq * YN.x; } \
} while (0)

// one sub-step over computed rows [LO, HI)
#define SSTEP(CUR, PRV, LO, HI, SIDX) do {                                     \
    float xsv = xs_l[SIDX];                                                    \
    _Pragma("unroll")                                                          \
    for (int r = (LO); r < (HI); r++) {                                        \
        v2f y;                                                                 \
        ROWC(CUR, PRV, r, xsv, y);                                             \
        PRV[r] = y;                                                            \
    }                                                                          \
} while (0)

    __syncthreads();   // U/D zeros visible

#pragma unroll 1
    for (int ss = 0; ss < NSS; ss++) {
        // ---- exchange: refresh ghost rows (one barrier pair per 4 steps) ----
        U[w][0][l] = yc[4];  U[w][1][l] = yc[5];
        U[w][2][l] = yc[6];  U[w][3][l] = yc[7];
        U[w][4][l] = yp[4];  U[w][5][l] = yp[5];  U[w][6][l] = yp[6];
        D[w + 1][0][l] = yc[10]; D[w + 1][1][l] = yc[11];
        D[w + 1][2][l] = yc[12]; D[w + 1][3][l] = yc[13];
        D[w + 1][4][l] = yp[11]; D[w + 1][5][l] = yp[12]; D[w + 1][6][l] = yp[13];
        __syncthreads();
        yc[14] = U[w + 1][0][l]; yc[15] = U[w + 1][1][l];
        yc[16] = U[w + 1][2][l]; yc[17] = U[w + 1][3][l];
        yp[14] = U[w + 1][4][l]; yp[15] = U[w + 1][5][l]; yp[16] = U[w + 1][6][l];
        yc[0] = D[w][0][l]; yc[1] = D[w][1][l];
        yc[2] = D[w][2][l]; yc[3] = D[w][3][l];
        yp[1] = D[w][4][l]; yp[2] = D[w][5][l]; yp[3] = D[w][6][l];
        __syncthreads();   // reads done before next superstep's writes

        // ---- 4 register-only steps with shrinking validity ----
        SSTEP(yc, yp, 1, 17, 4 * ss + 0);   // new cur -> yp
        SSTEP(yp, yc, 2, 16, 4 * ss + 1);   // new cur -> yc
        SSTEP(yc, yp, 3, 15, 4 * ss + 2);   // new cur -> yp
        SSTEP(yp, yc, 4, 14, 4 * ss + 3);   // new cur -> yc
    }
#undef SSTEP
#undef ROWC
    // yc = y(t_end) valid on band rows [4,14); yp = y(t_end-1) valid [3,15)

    // store out-tile: rows [16bi,16bi+16), lanes 16..47
#pragma unroll
    for (int i = HC; i < HC + RPL; i++) {
        int gi = row0 + i;
        if (gi >= 16 * bi && gi < 16 * bi + 16 && l >= 16 && l < 48) {
            int idx = gi * NXY + gj;
            *(v2f*)(ncurg + idx) = yc[i];
            *(v2f*)(nprvg + idx) = yp[i];
        }
    }
    if (wave_prb && prbm == 1.f) ws[I_OFF + b * 3 + bj] += pacc;
}

__global__ void final_k(const float* __restrict__ ws, float* __restrict__ out) {
    int t = threadIdx.x;
    if (t < 12) {
        const float* I = ws + I_OFF;
        int b = t / 3;
        float s = I[3 * b] + I[3 * b + 1] + I[3 * b + 2];
        out[t] = I[t] / s;
    }
}

extern "C" void kernel_launch(void* const* d_in, const int* in_sizes, int n_in,
                              void* d_out, int out_size, void* d_ws, size_t ws_size,
                              hipStream_t stream) {
    const float* x   = (const float*)d_in[0];   // (4,256) fp32
    const float* rho = (const float*)d_in[1];   // (192,192) fp32
    float* ws  = (float*)d_ws;
    float* out = (float*)d_out;

    setup_k<<<256, 256, 0, stream>>>(rho, ws);
    for (int c = 0; c < NCHUNK; c++)
        chunk_k<<<NBLKS, TPB, 0, stream>>>(x, ws, c);
    final_k<<<1, 64, 0, stream>>>(ws, out);
}

// Round 7
// 256.207 us; speedup vs baseline: 1.0716x; 1.0716x over previous
//
#include <hip/hip_runtime.h>
#include <math.h>

#define NXY    192
#define CELLS  (NXY*NXY)
#define NBATCH 4
#define NSTEPS 256
#define TCH    32                 // steps per chunk (= halo width)
#define NCHUNK (NSTEPS/TCH)       // 8
#define TPB    1024               // 16 waves -> 4 waves/SIMD (hide dep stalls)
#define NWAVE  16
#define RPL    5                  // rows per wave band (80 rows / 16 waves)
#define NBLKS  144                // 12 row-tiles x 3 col-tiles x 4 batches
// in-tile 128 wide x 80 tall; out-tile 64 wide x 16 tall (same as R5)

// workspace layout (float offsets)
#define K3_OFF (16*CELLS)
#define A1_OFF (K3_OFF + CELLS)
#define I_OFF  (A1_OFF + CELLS)

typedef float v2f __attribute__((ext_vector_type(2)));

__device__ __forceinline__ float dpp_up1(float v) {
    int r = __builtin_amdgcn_update_dpp(0, __builtin_bit_cast(int, v),
                                        0x138, 0xf, 0xf, true); // wave_shr:1
    return __builtin_bit_cast(float, r);
}
__device__ __forceinline__ float dpp_dn1(float v) {
    int r = __builtin_amdgcn_update_dpp(0, __builtin_bit_cast(int, v),
                                        0x130, 0xf, 0xf, true); // wave_shl:1
    return __builtin_bit_cast(float, r);
}

__device__ __forceinline__ float pml_prof(int i) {
    int t;
    if (i <= 20)            t = 20 - i;
    else if (i >= NXY - 21) t = i - (NXY - 21);
    else                    return 0.0f;
    float u  = (float)t * 0.05f;
    float u2 = u * u;
    return 3.0f * u2 * u2;
}

__global__ void setup_k(const float* __restrict__ rho, float* __restrict__ ws) {
    int idx    = blockIdx.x * blockDim.x + threadIdx.x;
    int stride = gridDim.x * blockDim.x;
    for (int k = idx; k < 8 * CELLS; k += stride) ws[k] = 0.0f;
    const float IH2 = (float)(1.0 / (2.01 * 2.01));
    for (int k = idx; k < CELLS; k += stride) {
        int i = k / NXY, j = k % NXY;
        float r0 = rho[k];
        float ru = (i > 0)       ? rho[k - NXY] : 0.0f;
        float rd = (i < NXY - 1) ? rho[k + NXY] : 0.0f;
        float rl = (j > 0)       ? rho[k - 1]   : 0.0f;
        float rr2 = (j < NXY - 1) ? rho[k + 1]  : 0.0f;
        float lpf = 0.5f * r0 + 0.125f * ((ru + rd) + (rl + rr2));
        float p   = 0.5f * (1.0f + tanhf(100.0f * (lpf - 0.5f)));
        float c   = 1.0f - 0.1f * p;
        float c2h = c * c * IH2;
        float bx = pml_prof(i), by = pml_prof(j);
        float bb = sqrtf(bx * bx + by * by);
        float a1 = 1.0f / (1.0f + 0.5f * bb);
        ws[K3_OFF + k] = a1 * c2h;     // K
        ws[A1_OFF + k] = a1;           // A1 (Q derived at load)
    }
    if (idx < 12) ws[I_OFF + idx] = 0.0f;
}

__global__ __launch_bounds__(TPB, 1)
void chunk_k(const float* __restrict__ x, float* __restrict__ ws, int chunk) {
    int blk = blockIdx.x;
    int b  = blk / 36;                // batch
    int rr = blk % 36;
    int bi = rr / 3, bj = rr % 3;     // 12 row-tiles x 3 col-tiles
    int I0 = 16 * bi - 32;            // in-tile row origin (80 rows)
    int J0 = 64 * bj - 32;            // in-tile col origin (128 cols)
    int t  = threadIdx.x;
    int w  = t >> 6;                  // wave 0..15, owns rows [5w, 5w+5)
    int l  = t & 63;                  // lane: local cols 2l, 2l+1
    int row0 = I0 + RPL * w;
    int gj   = J0 + 2 * l;

    // [parity][top/bot][slot 0..17][lane]; wave w writes slot w+1;
    // reads up from slot w (bot rows), down from slot w+2 (top rows);
    // slots 0 and 17 stay zero forever (outside in-tile)
    __shared__ v2f hb[2][2][NWAVE + 2][64];
    __shared__ float xs_l[TCH];
    for (int k = t; k < 2 * 2 * (NWAVE + 2) * 64; k += TPB)
        ((v2f*)hb)[k] = (v2f){0.f, 0.f};
    if (t < TCH) xs_l[t] = x[b * NSTEPS + chunk * TCH + t];

    const float* kg = ws + K3_OFF;
    const float* ag = ws + A1_OFF;
    int pin = chunk & 1, pout = pin ^ 1;
    const float* curg  = ws + ((pin  * 2 + 0) * NBATCH + b) * CELLS;
    const float* prvg  = ws + ((pin  * 2 + 1) * NBATCH + b) * CELLS;
    float*       ncurg = ws + ((pout * 2 + 0) * NBATCH + b) * CELLS;
    float*       nprvg = ws + ((pout * 2 + 1) * NBATCH + b) * CELLS;

    // per-lane state: 4 v2f arrays x 5 rows = 40 VGPRs
    v2f yc[RPL], yp[RPL], Qa[RPL], Ka[RPL];
    bool cok = (gj >= 0 && gj < NXY);
#pragma unroll
    for (int r = 0; r < RPL; r++) {
        int gi = row0 + r;
        bool ok = cok && gi >= 0 && gi < NXY;
        v2f kv = {0.f,0.f}, av = {0.f,0.f}, cv = {0.f,0.f}, pv = {0.f,0.f};
        if (ok) {
            int idx = gi * NXY + gj;
            kv = *(const v2f*)(kg + idx);
            av = *(const v2f*)(ag + idx);
            cv = *(const v2f*)(curg + idx);
            pv = *(const v2f*)(prvg + idx);
        }
        yc[r] = cv; yp[r] = pv; Ka[r] = kv;
        // out-of-domain: K=0,Q=0 -> yn = c = 0 forever
        Qa[r] = ok ? (v2f){1.f - 2.f * av.x, 1.f - 2.f * av.y} : (v2f){0.f, 0.f};
    }

    // source (40,96): even column in every owning tile
    int sr = 40 - I0, sc = 96 - J0;
    bool wave_src = (sc >= 0 && sc < 128) && (sr >= RPL * w) && (sr < RPL * w + RPL);
    int src_rl = sr - RPL * w;
    float srcm = (2 * l == sc) ? 1.f : 0.f;

    // probe: row 160 (bi==10 -> local row 32, wave 6, r=2), col 48*(bj+1)
    bool blk_prb = (bi == 10);
    int pr = 160 - I0;
    bool wave_prb = blk_prb && (pr >= RPL * w) && (pr < RPL * w + RPL);
    int prb_rl = pr - RPL * w;
    float prbm = (2 * l == (48 * (bj + 1) - J0)) ? 1.f : 0.f;
    float pacc = 0.f;

    v2f uph, dnh;

// row update: yn = c + Q*(p-c) + K*(S-4c) — packed fp32
#define ROWC(CUR, PRV, rr_, UP, DN, YN) do {                                   \
    v2f cv = CUR[rr_];                                                         \
    float lf0 = dpp_up1(cv.y);                                                 \
    float rt1 = dpp_dn1(cv.x);                                                 \
    v2f h = (v2f){lf0, rt1} + __builtin_shufflevector(cv, cv, 1, 0);           \
    v2f S = ((UP) + (DN)) + h;                                                 \
    YN = cv + Qa[rr_] * (PRV[rr_] - cv) + Ka[rr_] * (S - 4.0f * cv);           \
    if (wave_src && (rr_) == src_rl) YN.x += srcm * xsv;                       \
    if (wave_prb && (rr_) == prb_rl) { float tq = prbm * YN.x; pacc += tq * YN.x; } \
} while (0)

// boundary rows first (early LDS write), interior hides it; halo read after
// barrier is first used next step
#define STEP(CUR, PRV, PH, SIDX) do {                                          \
    float xsv = xs_l[SIDX];                                                    \
    v2f t0, t4;                                                                \
    ROWC(CUR, PRV, 0, uph,    CUR[1], t0);                                     \
    ROWC(CUR, PRV, 4, CUR[3], dnh,    t4);                                     \
    hb[PH][0][w + 1][l] = t0;                                                  \
    hb[PH][1][w + 1][l] = t4;                                                  \
    PRV[0] = t0; PRV[4] = t4;                                                  \
    _Pragma("unroll")                                                          \
    for (int r = 1; r <= 3; r++) {                                             \
        v2f y;                                                                 \
        ROWC(CUR, PRV, r, CUR[r - 1], CUR[r + 1], y);                          \
        PRV[r] = y;                                                            \
    }                                                                          \
    __syncthreads();                                                           \
    uph = hb[PH][1][w][l];                                                     \
    dnh = hb[PH][0][w + 2][l];                                                 \
} while (0)

    // prologue halo exchange (parity 0)
    hb[0][0][w + 1][l] = yc[0];
    hb[0][1][w + 1][l] = yc[4];
    __syncthreads();
    uph = hb[0][1][w][l];
    dnh = hb[0][0][w + 2][l];

#pragma unroll 1
    for (int s2 = 0; s2 < TCH / 2; s2++) {
        STEP(yc, yp, 1, 2 * s2);        // new cur -> yp, writes hb[1]
        STEP(yp, yc, 0, 2 * s2 + 1);    // new cur -> yc, writes hb[0]
    }
#undef STEP
#undef ROWC
    // yc = y(t_end), yp = y(t_end - 1)

    // store out-tile: rows [16bi,16bi+16), lanes 16..47
#pragma unroll
    for (int r = 0; r < RPL; r++) {
        int gi = row0 + r;
        if (gi >= 16 * bi && gi < 16 * bi + 16 && l >= 16 && l < 48) {
            int idx = gi * NXY + gj;
            *(v2f*)(ncurg + idx) = yc[r];
            *(v2f*)(nprvg + idx) = yp[r];
        }
    }
    if (wave_prb && prbm == 1.f) ws[I_OFF + b * 3 + bj] += pacc;
}

__global__ void final_k(const float* __restrict__ ws, float* __restrict__ out) {
    int t = threadIdx.x;
    if (t < 12) {
        const float* I = ws + I_OFF;
        int b = t / 3;
        float s = I[3 * b] + I[3 * b + 1] + I[3 * b + 2];
        out[t] = I[t] / s;
    }
}

extern "C" void kernel_launch(void* const* d_in, const int* in_sizes, int n_in,
                              void* d_out, int out_size, void* d_ws, size_t ws_size,
                              hipStream_t stream) {
    const float* x   = (const float*)d_in[0];   // (4,256) fp32
    const float* rho = (const float*)d_in[1];   // (192,192) fp32
    float* ws  = (float*)d_ws;
    float* out = (float*)d_out;

    setup_k<<<256, 256, 0, stream>>>(rho, ws);
    for (int c = 0; c < NCHUNK; c++)
        chunk_k<<<NBLKS, TPB, 0, stream>>>(x, ws, c);
    final_k<<<1, 64, 0, stream>>>(ws, out);
}